// Round 1
// baseline (999.847 us; speedup 1.0000x reference)
//
#include <hip/hip_runtime.h>
#include <math.h>

// Problem constants
#define BB 2
#define CC 64
#define NN 4096      // 16*16*16
#define CN (CC*NN)   // 262144
#define NJ 4         // j-split chunks for flash partials

// Workspace layout (floats). Total 5,963,776 floats = 23.9 MB.
#define OFF_XPE  0
#define OFF_Q    524288
#define OFF_K    1048576
#define OFF_V    1572864
#define OFF_TSA  2097152
#define OFF_GSA  2621440
#define OFF_MT   3145728
#define OFF_NT   3211264
#define OFF_WVT  3276800
#define OFF_PM   3801088
#define OFF_PL   3833856
#define OFF_PACC 3866624

// ---------------- PE + x_pe ----------------
__device__ __forceinline__ float pe_val(int c, int hx, int wy, int dz) {
    // cpe=22, 11 freqs; ch 0..21 -> h axis, 22..43 -> w axis, 44..63 -> d axis
    int pos, c2;
    if (c < 22)      { pos = hx; c2 = c; }
    else if (c < 44) { pos = wy; c2 = c - 22; }
    else             { pos = dz; c2 = c - 44; }
    int is_cos = (c2 >= 11);
    int k = c2 - (is_cos ? 11 : 0);
    // inv_freq[k] = 10000^(-k/11) = 2^(-k*log2(10000)/11)
    float freq = exp2f(-1.2079738526863135f * (float)k);
    float arg = (float)pos * freq;
    return is_cos ? cosf(arg) : sinf(arg);
}

__global__ __launch_bounds__(256) void k_xpe(const float* __restrict__ x,
                                             float* __restrict__ xpe) {
    int idx = blockIdx.x * 256 + threadIdx.x;   // < B*C*N
    int pos = idx & (NN - 1);
    int c = (idx >> 12) & 63;
    int dz = pos & 15, wy = (pos >> 4) & 15, hx = pos >> 8;
    xpe[idx] = x[idx] + pe_val(c, hx, wy, dz);
}

// ---------------- QKV projection ----------------
// Q[b][i][d] = sum_c xpe[b][c][i] * W[c][d].  block: (i-chunk 256, mat, b)
__global__ __launch_bounds__(256) void k_qkv(const float* __restrict__ xpe,
                                             const float* __restrict__ Wq,
                                             const float* __restrict__ Wk,
                                             const float* __restrict__ Wv,
                                             float* __restrict__ outbase) {
    __shared__ float sW[64 * 64];
    int t = threadIdx.x;
    int mat = blockIdx.y, b = blockIdx.z;
    const float* W = (mat == 0) ? Wq : (mat == 1) ? Wk : Wv;
    float* out = outbase + (size_t)mat * (BB * NN * CC);

    float4* sW4 = (float4*)sW;
    const float4* W4 = (const float4*)W;
    #pragma unroll
    for (int j = 0; j < 4; j++) sW4[j * 256 + t] = W4[j * 256 + t];
    __syncthreads();

    int i = blockIdx.x * 256 + t;
    float acc[64];
    #pragma unroll
    for (int d = 0; d < 64; d++) acc[d] = 0.f;

    const float* xp = xpe + b * CN + i;
    for (int c = 0; c < 64; c++) {
        float xv = xp[c * NN];
        #pragma unroll
        for (int d4 = 0; d4 < 16; d4++) {
            float4 wv = sW4[c * 16 + d4];
            acc[4 * d4 + 0] += xv * wv.x;
            acc[4 * d4 + 1] += xv * wv.y;
            acc[4 * d4 + 2] += xv * wv.z;
            acc[4 * d4 + 3] += xv * wv.w;
        }
    }
    float4* o4 = (float4*)(out + ((size_t)(b * NN + i)) * 64);
    #pragma unroll
    for (int d4 = 0; d4 < 16; d4++)
        o4[d4] = make_float4(acc[4*d4], acc[4*d4+1], acc[4*d4+2], acc[4*d4+3]);
}

// ---------------- Conv3d (M, Nk, Wv fused; 80 output channels) ----------------
// block: (pos-tile of 128 -> 32, ocg of 16 -> 5, b).  thread: 4 oc x 2 pos.
__global__ __launch_bounds__(256) void k_conv(const float* __restrict__ xpe,
                                              const float* __restrict__ qw, const float* __restrict__ qb,
                                              const float* __restrict__ kw, const float* __restrict__ kb,
                                              const float* __restrict__ vw, const float* __restrict__ vb,
                                              float* __restrict__ Mt, float* __restrict__ Nt,
                                              float* __restrict__ Wvt) {
    __shared__ float sX[16 * 128];
    __shared__ float sW[16 * 16];
    int t = threadIdx.x;
    int b = blockIdx.z, oc0 = blockIdx.y * 16;
    int pos0 = blockIdx.x * 128;
    int ocq = t >> 6;    // 0..3 -> oc' = ocq*4+j
    int pp2 = t & 63;    // pos pair -> pos = pos0 + pp2*2 + {0,1}

    float acc[4][2];
    #pragma unroll
    for (int j = 0; j < 4; j++) { acc[j][0] = 0.f; acc[j][1] = 0.f; }

    int icp_s = t >> 4;          // staging row
    int e0 = (t & 15) * 8;       // staging cols
    int ocw = t & 15;

    for (int tap = 0; tap < 27; tap++) {
        int dh = tap / 9 - 1, dw = (tap / 3) % 3 - 1, dd = tap % 3 - 1;
        int shift = dh * 256 + dw * 16 + dd;
        for (int icc = 0; icc < 4; icc++) {
            __syncthreads();
            { // stage X tile (shifted, masked)
                const float* src = xpe + b * CN + (icc * 16 + icp_s) * NN;
                #pragma unroll
                for (int e = 0; e < 8; e++) {
                    int pos = pos0 + e0 + e;
                    int hx = pos >> 8, wy = (pos >> 4) & 15, dz = pos & 15;
                    int h2 = hx + dh, w2 = wy + dw, d2 = dz + dd;
                    bool ok = ((unsigned)h2 < 16u) && ((unsigned)w2 < 16u) && ((unsigned)d2 < 16u);
                    sX[icp_s * 128 + e0 + e] = ok ? src[pos + shift] : 0.f;
                }
                // stage W: one element per thread: sW[ic][oc']
                int oc = oc0 + ocw;
                const float* wsrc; int ocs;
                if (oc < 8)       { wsrc = qw; ocs = oc; }
                else if (oc < 16) { wsrc = kw; ocs = oc - 8; }
                else              { wsrc = vw; ocs = oc - 16; }
                sW[icp_s * 16 + ocw] = wsrc[(ocs * 64 + icc * 16 + icp_s) * 27 + tap];
            }
            __syncthreads();
            #pragma unroll
            for (int icp = 0; icp < 16; icp++) {
                float4 w4 = *(const float4*)&sW[icp * 16 + ocq * 4];
                float2 x2 = *(const float2*)&sX[icp * 128 + pp2 * 2];
                acc[0][0] += w4.x * x2.x;  acc[0][1] += w4.x * x2.y;
                acc[1][0] += w4.y * x2.x;  acc[1][1] += w4.y * x2.y;
                acc[2][0] += w4.z * x2.x;  acc[2][1] += w4.z * x2.y;
                acc[3][0] += w4.w * x2.x;  acc[3][1] += w4.w * x2.y;
            }
        }
    }
    // bias + transposed store: M/N -> (b,n,8), Wv -> (b,n,64)
    #pragma unroll
    for (int p = 0; p < 2; p++) {
        int pos = pos0 + pp2 * 2 + p;
        #pragma unroll
        for (int j = 0; j < 4; j++) {
            int oc = oc0 + ocq * 4 + j;
            float v = acc[j][p];
            if (oc < 8)       Mt[((size_t)(b * NN + pos)) * 8 + oc] = v + qb[oc];
            else if (oc < 16) Nt[((size_t)(b * NN + pos)) * 8 + (oc - 8)] = v + kb[oc - 8];
            else              Wvt[((size_t)(b * NN + pos)) * 64 + (oc - 16)] = v + vb[oc - 16];
        }
    }
}

// ---------------- Flash attention partials (j-split) ----------------
// Q rows of width DQ (scaled by qscale = log2e * scale), K (n,DQ), V (n,64).
// block: (i-tile of 32 -> 128, jc -> NJ, b).  thread: r = t>>3 (row), u = t&7 (slice).
template<int DQ>
__global__ __launch_bounds__(256) void k_flash_part(const float* __restrict__ Qm,
                                                    const float* __restrict__ Km,
                                                    const float* __restrict__ Vm,
                                                    float* __restrict__ pM, float* __restrict__ pL,
                                                    float* __restrict__ pAcc, float qscale) {
    constexpr int E = DQ / 8;
    __shared__ float sK[64 * DQ];
    __shared__ float sV[64 * 64];
    int t = threadIdx.x;
    int b = blockIdx.z, jc = blockIdx.y, it = blockIdx.x;
    int r = t >> 3, u = t & 7;
    int i = it * 32 + r;

    float q[E];
    const float* qrow = Qm + ((size_t)(b * NN + i)) * DQ + u * E;
    #pragma unroll
    for (int e = 0; e < E; e++) q[e] = qrow[e] * qscale;

    float m = -1e30f, l = 0.f;
    float acc[8];
    #pragma unroll
    for (int e = 0; e < 8; e++) acc[e] = 0.f;

    int j0 = jc * (NN / NJ);
    for (int jt = 0; jt < (NN / NJ) / 64; jt++) {
        int jbase = j0 + jt * 64;
        __syncthreads();
        {
            const float4* src = (const float4*)(Km + ((size_t)(b * NN + jbase)) * DQ);
            float4* dst = (float4*)sK;
            for (int idx = t; idx < 64 * DQ / 4; idx += 256) dst[idx] = src[idx];
            const float4* vs = (const float4*)(Vm + ((size_t)(b * NN + jbase)) * 64);
            float4* vd = (float4*)sV;
            for (int idx = t; idx < 1024; idx += 256) vd[idx] = vs[idx];
        }
        __syncthreads();
        #pragma unroll
        for (int hh = 0; hh < 2; hh++) {
            float s[32];
            #pragma unroll
            for (int kj = 0; kj < 32; kj++) {
                int kr = hh * 32 + kj;
                float sp = 0.f;
                #pragma unroll
                for (int e = 0; e < E; e++) sp += q[e] * sK[kr * DQ + u * E + e];
                sp += __shfl_xor(sp, 1, 64);
                sp += __shfl_xor(sp, 2, 64);
                sp += __shfl_xor(sp, 4, 64);
                s[kj] = sp;   // score * log2e
            }
            float tm = s[0];
            #pragma unroll
            for (int kj = 1; kj < 32; kj++) tm = fmaxf(tm, s[kj]);
            float mn = fmaxf(m, tm);
            float corr = exp2f(m - mn);
            m = mn;
            float ps = 0.f;
            #pragma unroll
            for (int kj = 0; kj < 32; kj++) { s[kj] = exp2f(s[kj] - m); ps += s[kj]; }
            l = l * corr + ps;
            #pragma unroll
            for (int e = 0; e < 8; e++) acc[e] *= corr;
            #pragma unroll
            for (int kj = 0; kj < 32; kj++) {
                const float* vr = sV + (hh * 32 + kj) * 64 + u * 8;
                float p = s[kj];
                #pragma unroll
                for (int e = 0; e < 8; e++) acc[e] += p * vr[e];
            }
        }
    }
    if (u == 0) {
        pM[(size_t)(b * NJ + jc) * NN + i] = m;
        pL[(size_t)(b * NJ + jc) * NN + i] = l;
    }
    float* pa = pAcc + ((size_t)(b * NJ + jc) * NN + i) * 64 + u * 8;
    #pragma unroll
    for (int e = 0; e < 8; e++) pa[e] = acc[e];
}

// ---------------- Reduce j-split partials ----------------
__global__ __launch_bounds__(256) void k_reduce(const float* __restrict__ pM,
                                                const float* __restrict__ pL,
                                                const float* __restrict__ pAcc,
                                                float* __restrict__ Out) {
    int idx = blockIdx.x * 256 + threadIdx.x;  // b*N*64
    int c = idx & 63;
    int i = (idx >> 6) & (NN - 1);
    int b = idx >> 18;
    float mv[NJ];
    float M = -1e30f;
    #pragma unroll
    for (int jc = 0; jc < NJ; jc++) {
        mv[jc] = pM[(size_t)(b * NJ + jc) * NN + i];
        M = fmaxf(M, mv[jc]);
    }
    float L = 0.f, a = 0.f;
    #pragma unroll
    for (int jc = 0; jc < NJ; jc++) {
        float w = exp2f(mv[jc] - M);
        L += pL[(size_t)(b * NJ + jc) * NN + i] * w;
        a += pAcc[((size_t)(b * NJ + jc) * NN + i) * 64 + c] * w;
    }
    Out[idx] = a / L;
}

// ---------------- Combine: out = lam1*tsa + lam2*gsa + xpe (transpose (b,n,c)->(b,c,n)) ----------------
__global__ __launch_bounds__(256) void k_combine(const float* __restrict__ tsa,
                                                 const float* __restrict__ gsa,
                                                 const float* __restrict__ xpe,
                                                 const float* __restrict__ lam1,
                                                 const float* __restrict__ lam2,
                                                 float* __restrict__ out) {
    __shared__ float sT[64 * 65];
    __shared__ float sG[64 * 65];
    int t = threadIdx.x;
    int b = blockIdx.y;
    int pos0 = blockIdx.x * 64;
    float l1 = lam1[0], l2 = lam2[0];

    int pp = t >> 2, seg = t & 3;
    const float4* ts = (const float4*)(tsa + ((size_t)(b * NN + pos0 + pp)) * 64);
    const float4* gs = (const float4*)(gsa + ((size_t)(b * NN + pos0 + pp)) * 64);
    #pragma unroll
    for (int j = 0; j < 4; j++) {
        float4 v = ts[seg * 4 + j];
        int cb = seg * 16 + j * 4;
        sT[pp * 65 + cb + 0] = v.x; sT[pp * 65 + cb + 1] = v.y;
        sT[pp * 65 + cb + 2] = v.z; sT[pp * 65 + cb + 3] = v.w;
        float4 g = gs[seg * 4 + j];
        sG[pp * 65 + cb + 0] = g.x; sG[pp * 65 + cb + 1] = g.y;
        sG[pp * 65 + cb + 2] = g.z; sG[pp * 65 + cb + 3] = g.w;
    }
    __syncthreads();

    int c = t >> 2;
    int ps = (t & 3) * 16;
    size_t obase = ((size_t)(b * 64 + c)) * NN + pos0 + ps;
    const float* xp = xpe + obase;
    float* o = out + obase;
    #pragma unroll
    for (int j = 0; j < 16; j += 4) {
        float4 ov;
        ov.x = l1 * sT[(ps + j + 0) * 65 + c] + l2 * sG[(ps + j + 0) * 65 + c] + xp[j + 0];
        ov.y = l1 * sT[(ps + j + 1) * 65 + c] + l2 * sG[(ps + j + 1) * 65 + c] + xp[j + 1];
        ov.z = l1 * sT[(ps + j + 2) * 65 + c] + l2 * sG[(ps + j + 2) * 65 + c] + xp[j + 2];
        ov.w = l1 * sT[(ps + j + 3) * 65 + c] + l2 * sG[(ps + j + 3) * 65 + c] + xp[j + 3];
        *(float4*)(o + j) = ov;
    }
}

extern "C" void kernel_launch(void* const* d_in, const int* in_sizes, int n_in,
                              void* d_out, int out_size, void* d_ws, size_t ws_size,
                              hipStream_t stream) {
    const float* x    = (const float*)d_in[0];
    const float* Wq   = (const float*)d_in[1];
    const float* Wk   = (const float*)d_in[2];
    const float* Wv   = (const float*)d_in[3];
    const float* qw   = (const float*)d_in[4];
    const float* qb   = (const float*)d_in[5];
    const float* kw   = (const float*)d_in[6];
    const float* kb   = (const float*)d_in[7];
    const float* vw   = (const float*)d_in[8];
    const float* vb   = (const float*)d_in[9];
    const float* lam1 = (const float*)d_in[10];
    const float* lam2 = (const float*)d_in[11];
    float* out = (float*)d_out;
    float* ws = (float*)d_ws;

    // 1. x_pe
    k_xpe<<<dim3(BB * CC * NN / 256), dim3(256), 0, stream>>>(x, ws + OFF_XPE);
    // 2. Q,K,V projections
    k_qkv<<<dim3(16, 3, BB), dim3(256), 0, stream>>>(ws + OFF_XPE, Wq, Wk, Wv, ws + OFF_Q);
    // 3. convs -> Mt, Nt, Wvt (transposed layouts)
    k_conv<<<dim3(32, 5, BB), dim3(256), 0, stream>>>(ws + OFF_XPE, qw, qb, kw, kb, vw, vb,
                                                      ws + OFF_MT, ws + OFF_NT, ws + OFF_WVT);
    // 4. TSA flash partials + reduce  (scale = log2(e)/sqrt(64))
    k_flash_part<64><<<dim3(128, NJ, BB), dim3(256), 0, stream>>>(
        ws + OFF_Q, ws + OFF_K, ws + OFF_V, ws + OFF_PM, ws + OFF_PL, ws + OFF_PACC,
        0.18033688011112042f);
    k_reduce<<<dim3(BB * NN * CC / 256), dim3(256), 0, stream>>>(
        ws + OFF_PM, ws + OFF_PL, ws + OFF_PACC, ws + OFF_TSA);
    // 5. GSA flash partials + reduce (no sqrt scale)
    k_flash_part<8><<<dim3(128, NJ, BB), dim3(256), 0, stream>>>(
        ws + OFF_MT, ws + OFF_NT, ws + OFF_WVT, ws + OFF_PM, ws + OFF_PL, ws + OFF_PACC,
        1.4426950408889634f);
    k_reduce<<<dim3(BB * NN * CC / 256), dim3(256), 0, stream>>>(
        ws + OFF_PM, ws + OFF_PL, ws + OFF_PACC, ws + OFF_GSA);
    // 6. combine
    k_combine<<<dim3(64, BB), dim3(256), 0, stream>>>(
        ws + OFF_TSA, ws + OFF_GSA, ws + OFF_XPE, lam1, lam2, out);
}

// Round 2
// 435.072 us; speedup vs baseline: 2.2981x; 2.2981x over previous
//
#include <hip/hip_runtime.h>
#include <math.h>

// Problem constants
#define BB 2
#define CC 64
#define NN 4096      // 16*16*16
#define CN (CC*NN)   // 262144
#define NJ 4         // j-split chunks for flash partials

#define LOG2E 1.4426950408889634f
#define QSCALE 0.18033688011112042f   // log2e / sqrt(64)

typedef __attribute__((ext_vector_type(8))) short short8;
typedef __attribute__((ext_vector_type(4))) float float4v;
typedef unsigned short ushortT;

__device__ __forceinline__ ushortT f2bf(float x) {
    union { float f; unsigned u; } v; v.f = x;
    unsigned r = v.u + 0x7FFF + ((v.u >> 16) & 1);   // RNE
    return (ushortT)(r >> 16);
}

// ---------------- PE + x_pe ----------------
__device__ __forceinline__ float pe_val(int c, int hx, int wy, int dz) {
    int pos, c2;
    if (c < 22)      { pos = hx; c2 = c; }
    else if (c < 44) { pos = wy; c2 = c - 22; }
    else             { pos = dz; c2 = c - 44; }
    int is_cos = (c2 >= 11);
    int k = c2 - (is_cos ? 11 : 0);
    float freq = exp2f(-1.2079738526863135f * (float)k);
    float arg = (float)pos * freq;
    return is_cos ? cosf(arg) : sinf(arg);
}

__global__ __launch_bounds__(256) void k_xpe(const float* __restrict__ x,
                                             float* __restrict__ xpe) {
    int idx = blockIdx.x * 256 + threadIdx.x;
    int pos = idx & (NN - 1);
    int c = (idx >> 12) & 63;
    int dz = pos & 15, wy = (pos >> 4) & 15, hx = pos >> 8;
    xpe[idx] = x[idx] + pe_val(c, hx, wy, dz);
}

// ---------------- QKV projection (bf16 out; V transposed) ----------------
__global__ __launch_bounds__(256) void k_qkv(const float* __restrict__ xpe,
                                             const float* __restrict__ Wq,
                                             const float* __restrict__ Wk,
                                             const float* __restrict__ Wv,
                                             ushortT* __restrict__ Qb,
                                             ushortT* __restrict__ Kb,
                                             ushortT* __restrict__ Vtb) {
    __shared__ float sW[64 * 64];
    int t = threadIdx.x;
    int mat = blockIdx.y, b = blockIdx.z;
    const float* W = (mat == 0) ? Wq : (mat == 1) ? Wk : Wv;

    float4* sW4 = (float4*)sW;
    const float4* W4 = (const float4*)W;
    #pragma unroll
    for (int j = 0; j < 4; j++) sW4[j * 256 + t] = W4[j * 256 + t];
    __syncthreads();

    int i = blockIdx.x * 256 + t;
    float acc[64];
    #pragma unroll
    for (int d = 0; d < 64; d++) acc[d] = 0.f;

    const float* xp = xpe + b * CN + i;
    for (int c = 0; c < 64; c++) {
        float xv = xp[c * NN];
        #pragma unroll
        for (int d4 = 0; d4 < 16; d4++) {
            float4 wv = *(float4*)&sW[c * 64 + d4 * 4];
            acc[4 * d4 + 0] += xv * wv.x;
            acc[4 * d4 + 1] += xv * wv.y;
            acc[4 * d4 + 2] += xv * wv.z;
            acc[4 * d4 + 3] += xv * wv.w;
        }
    }
    if (mat < 2) {
        float sc = (mat == 0) ? QSCALE : 1.f;
        ushortT* o = ((mat == 0) ? Qb : Kb) + ((size_t)(b * NN + i)) * 64;
        #pragma unroll
        for (int d4 = 0; d4 < 16; d4++) {
            ushort4 u;
            u.x = f2bf(acc[4*d4+0] * sc); u.y = f2bf(acc[4*d4+1] * sc);
            u.z = f2bf(acc[4*d4+2] * sc); u.w = f2bf(acc[4*d4+3] * sc);
            *(ushort4*)(o + d4 * 4) = u;
        }
    } else {
        #pragma unroll
        for (int d = 0; d < 64; d++)
            Vtb[((size_t)(b * 64 + d)) * NN + i] = f2bf(acc[d]);
    }
}

// ---------------- Conv3d (M, Nk, Wv fused; 80 output channels; bf16 out) ----------------
__global__ __launch_bounds__(256) void k_conv(const float* __restrict__ xpe,
                                              const float* __restrict__ qw, const float* __restrict__ qb,
                                              const float* __restrict__ kw, const float* __restrict__ kb,
                                              const float* __restrict__ vw, const float* __restrict__ vb,
                                              ushortT* __restrict__ Mt, ushortT* __restrict__ Nt,
                                              ushortT* __restrict__ Wvt) {
    __shared__ float sX[16 * 128];
    __shared__ float sW[16 * 16];
    int t = threadIdx.x;
    int b = blockIdx.z, oc0 = blockIdx.y * 16;
    int pos0 = blockIdx.x * 128;
    int ocq = t >> 6;
    int pp2 = t & 63;

    float acc[4][2];
    #pragma unroll
    for (int j = 0; j < 4; j++) { acc[j][0] = 0.f; acc[j][1] = 0.f; }

    int icp_s = t >> 4;
    int e0 = (t & 15) * 8;
    int ocw = t & 15;

    for (int tap = 0; tap < 27; tap++) {
        int dh = tap / 9 - 1, dw = (tap / 3) % 3 - 1, dd = tap % 3 - 1;
        int shift = dh * 256 + dw * 16 + dd;
        for (int icc = 0; icc < 4; icc++) {
            __syncthreads();
            {
                const float* src = xpe + b * CN + (icc * 16 + icp_s) * NN;
                #pragma unroll
                for (int e = 0; e < 8; e++) {
                    int pos = pos0 + e0 + e;
                    int hx = pos >> 8, wy = (pos >> 4) & 15, dz = pos & 15;
                    int h2 = hx + dh, w2 = wy + dw, d2 = dz + dd;
                    bool ok = ((unsigned)h2 < 16u) && ((unsigned)w2 < 16u) && ((unsigned)d2 < 16u);
                    sX[icp_s * 128 + e0 + e] = ok ? src[pos + shift] : 0.f;
                }
                int oc = oc0 + ocw;
                const float* wsrc; int ocs;
                if (oc < 8)       { wsrc = qw; ocs = oc; }
                else if (oc < 16) { wsrc = kw; ocs = oc - 8; }
                else              { wsrc = vw; ocs = oc - 16; }
                sW[icp_s * 16 + ocw] = wsrc[(ocs * 64 + icc * 16 + icp_s) * 27 + tap];
            }
            __syncthreads();
            #pragma unroll
            for (int icp = 0; icp < 16; icp++) {
                float4 w4 = *(const float4*)&sW[icp * 16 + ocq * 4];
                float2 x2 = *(const float2*)&sX[icp * 128 + pp2 * 2];
                acc[0][0] += w4.x * x2.x;  acc[0][1] += w4.x * x2.y;
                acc[1][0] += w4.y * x2.x;  acc[1][1] += w4.y * x2.y;
                acc[2][0] += w4.z * x2.x;  acc[2][1] += w4.z * x2.y;
                acc[3][0] += w4.w * x2.x;  acc[3][1] += w4.w * x2.y;
            }
        }
    }
    #pragma unroll
    for (int p = 0; p < 2; p++) {
        int pos = pos0 + pp2 * 2 + p;
        #pragma unroll
        for (int j = 0; j < 4; j++) {
            int oc = oc0 + ocq * 4 + j;
            float v = acc[j][p];
            if (oc < 8)       Mt[((size_t)(b * NN + pos)) * 8 + oc] = f2bf((v + qb[oc]) * LOG2E);
            else if (oc < 16) Nt[((size_t)(b * NN + pos)) * 8 + (oc - 8)] = f2bf(v + kb[oc - 8]);
            else              Wvt[((size_t)(b * 64 + (oc - 16))) * NN + pos] = f2bf(v + vb[oc - 16]);
        }
    }
}

// ---------------- MFMA flash attention partials (j-split) ----------------
// Q: (B,N,DQ) bf16 pre-scaled by log2e*scale; K: (B,N,DQ) bf16; Vt: (B,64,N) bf16.
// grid: (N/64, NJ, B), 256 threads = 4 waves; wave handles 16 query rows.
template<int DQ>
__global__ __launch_bounds__(256) void k_flash_mfma(const ushortT* __restrict__ Qm,
                                                    const ushortT* __restrict__ Km,
                                                    const ushortT* __restrict__ Vt,
                                                    float* __restrict__ pM, float* __restrict__ pL,
                                                    float* __restrict__ pAcc) {
    constexpr int KCH = (DQ == 64) ? 2 : 1;
    __shared__ ushortT sP[4][16 * 64];   // per-wave 16x64 bf16, XOR-swizzled
    int t = threadIdx.x;
    int w = t >> 6, l = t & 63;
    int lane15 = l & 15, q = l >> 4;
    int b = blockIdx.z, jc = blockIdx.y;
    int i0 = blockIdx.x * 64 + w * 16;
    ushortT* myP = sP[w];

    // Q fragments (held for whole kernel)
    short8 qf[KCH];
    {
        const ushortT* qrow = Qm + ((size_t)(b * NN + i0 + lane15)) * DQ;
        #pragma unroll
        for (int kc = 0; kc < KCH; kc++) {
            if (DQ == 64) {
                qf[kc] = *(const short8*)(qrow + kc * 32 + q * 8);
            } else {
                short8 z = (short8)0;
                if (q == 0) z = *(const short8*)qrow;
                qf[kc] = z;
            }
        }
    }

    float m[4], l_[4];
    float4v O[4];
    #pragma unroll
    for (int r = 0; r < 4; r++) { m[r] = -3e38f; l_[r] = 0.f; }
    #pragma unroll
    for (int cs = 0; cs < 4; cs++) O[cs] = (float4v)0.f;

    const int jbase0 = jc * (NN / NJ);
    for (int jt = 0; jt < (NN / NJ) / 64; jt++) {
        int jb = jbase0 + jt * 64;

        // ---- S = Q K^T (16 x 64) ----
        short8 kf[4][KCH];
        #pragma unroll
        for (int sub = 0; sub < 4; sub++) {
            const ushortT* krow = Km + ((size_t)(b * NN + jb + sub * 16 + lane15)) * DQ;
            #pragma unroll
            for (int kc = 0; kc < KCH; kc++) {
                if (DQ == 64) kf[sub][kc] = *(const short8*)(krow + kc * 32 + q * 8);
                else { short8 z = (short8)0; if (q == 0) z = *(const short8*)krow; kf[sub][kc] = z; }
            }
        }
        float4v s[4];
        #pragma unroll
        for (int sub = 0; sub < 4; sub++) {
            float4v acc = (float4v)0.f;
            #pragma unroll
            for (int kc = 0; kc < KCH; kc++)
                acc = __builtin_amdgcn_mfma_f32_16x16x32_bf16(qf[kc], kf[sub][kc], acc, 0, 0, 0);
            s[sub] = acc;
        }

        // ---- online softmax (scores already in log2 domain) ----
        float mx[4];
        #pragma unroll
        for (int r = 0; r < 4; r++)
            mx[r] = fmaxf(fmaxf(s[0][r], s[1][r]), fmaxf(s[2][r], s[3][r]));
        #pragma unroll
        for (int r = 0; r < 4; r++) {
            mx[r] = fmaxf(mx[r], __shfl_xor(mx[r], 1));
            mx[r] = fmaxf(mx[r], __shfl_xor(mx[r], 2));
            mx[r] = fmaxf(mx[r], __shfl_xor(mx[r], 4));
            mx[r] = fmaxf(mx[r], __shfl_xor(mx[r], 8));
        }
        float corr[4];
        #pragma unroll
        for (int r = 0; r < 4; r++) {
            float mn = fmaxf(m[r], mx[r]);
            corr[r] = exp2f(m[r] - mn);
            m[r] = mn;
        }
        #pragma unroll
        for (int sub = 0; sub < 4; sub++)
            #pragma unroll
            for (int r = 0; r < 4; r++)
                s[sub][r] = exp2f(s[sub][r] - m[r]);
        float rs[4];
        #pragma unroll
        for (int r = 0; r < 4; r++) {
            rs[r] = (s[0][r] + s[1][r]) + (s[2][r] + s[3][r]);
            rs[r] += __shfl_xor(rs[r], 1);
            rs[r] += __shfl_xor(rs[r], 2);
            rs[r] += __shfl_xor(rs[r], 4);
            rs[r] += __shfl_xor(rs[r], 8);
            l_[r] = l_[r] * corr[r] + rs[r];
        }
        #pragma unroll
        for (int cs = 0; cs < 4; cs++)
            #pragma unroll
            for (int r = 0; r < 4; r++)
                O[cs][r] *= corr[r];

        // ---- P -> LDS (C-layout -> A-layout, XOR swizzle on 16B groups) ----
        #pragma unroll
        for (int sub = 0; sub < 4; sub++) {
            int jgrp = sub * 2 + (lane15 >> 3);
            int e = lane15 & 7;
            #pragma unroll
            for (int r = 0; r < 4; r++) {
                int row = q * 4 + r;
                myP[row * 64 + ((jgrp ^ (row & 7)) * 8 + e)] = f2bf(s[sub][r]);
            }
        }
        short8 pf[2];
        #pragma unroll
        for (int kc2 = 0; kc2 < 2; kc2++)
            pf[kc2] = *(const short8*)(myP + lane15 * 64 + (((kc2 * 4 + q) ^ (lane15 & 7)) * 8));

        // ---- O += P V ----
        #pragma unroll
        for (int sub = 0; sub < 4; sub++) {
            const ushortT* vrow = Vt + ((size_t)(b * 64 + sub * 16 + lane15)) * NN + jb;
            short8 vf0 = *(const short8*)(vrow + q * 8);
            short8 vf1 = *(const short8*)(vrow + 32 + q * 8);
            O[sub] = __builtin_amdgcn_mfma_f32_16x16x32_bf16(pf[0], vf0, O[sub], 0, 0, 0);
            O[sub] = __builtin_amdgcn_mfma_f32_16x16x32_bf16(pf[1], vf1, O[sub], 0, 0, 0);
        }
    }

    // ---- store partials ----
    size_t base = (size_t)(b * NJ + jc) * NN + i0;
    if (lane15 == 0) {
        #pragma unroll
        for (int r = 0; r < 4; r++) {
            pM[base + q * 4 + r] = m[r];
            pL[base + q * 4 + r] = l_[r];
        }
    }
    #pragma unroll
    for (int cs = 0; cs < 4; cs++)
        #pragma unroll
        for (int r = 0; r < 4; r++)
            pAcc[(base + q * 4 + r) * 64 + cs * 16 + lane15] = O[cs][r];
}

// ---------------- Reduce partials + fused epilogue (transpose, lam, +xpe) ----------------
// add_mode 0: out = lam*attn + xpe ; add_mode 1: out += lam*attn
__global__ __launch_bounds__(256) void k_reduce_out(const float* __restrict__ pM,
                                                    const float* __restrict__ pL,
                                                    const float* __restrict__ pAcc,
                                                    const float* __restrict__ xpe,
                                                    const float* __restrict__ lam,
                                                    float* __restrict__ out,
                                                    int add_mode) {
    __shared__ float sT[64][65];
    int t = threadIdx.x;
    int b = blockIdx.y;
    int n0 = blockIdx.x * 64;
    int pp = t >> 2, seg = t & 3;
    int n = n0 + pp;

    float mv[NJ], M = -3e38f;
    #pragma unroll
    for (int jc = 0; jc < NJ; jc++) {
        mv[jc] = pM[(size_t)(b * NJ + jc) * NN + n];
        M = fmaxf(M, mv[jc]);
    }
    float L = 0.f;
    float v[16];
    #pragma unroll
    for (int e = 0; e < 16; e++) v[e] = 0.f;
    #pragma unroll
    for (int jc = 0; jc < NJ; jc++) {
        float wgt = exp2f(mv[jc] - M);
        L += pL[(size_t)(b * NJ + jc) * NN + n] * wgt;
        const float4* pa = (const float4*)(pAcc + ((size_t)(b * NJ + jc) * NN + n) * 64 + seg * 16);
        #pragma unroll
        for (int e4 = 0; e4 < 4; e4++) {
            float4 x = pa[e4];
            v[4*e4+0] += wgt * x.x; v[4*e4+1] += wgt * x.y;
            v[4*e4+2] += wgt * x.z; v[4*e4+3] += wgt * x.w;
        }
    }
    float invL = 1.f / L;
    #pragma unroll
    for (int e = 0; e < 16; e++) sT[pp][seg * 16 + e] = v[e] * invL;
    __syncthreads();

    int c = t >> 2, ns = (t & 3) * 16;
    float la = lam[0];
    size_t ob = ((size_t)(b * 64 + c)) * NN + n0 + ns;
    if (!add_mode) {
        const float* xp = xpe + ob;
        #pragma unroll
        for (int j = 0; j < 16; j += 4) {
            float4 ov;
            ov.x = la * sT[ns + j + 0][c] + xp[j + 0];
            ov.y = la * sT[ns + j + 1][c] + xp[j + 1];
            ov.z = la * sT[ns + j + 2][c] + xp[j + 2];
            ov.w = la * sT[ns + j + 3][c] + xp[j + 3];
            *(float4*)(out + ob + j) = ov;
        }
    } else {
        #pragma unroll
        for (int j = 0; j < 16; j += 4) {
            float4 cur = *(const float4*)(out + ob + j);
            cur.x += la * sT[ns + j + 0][c];
            cur.y += la * sT[ns + j + 1][c];
            cur.z += la * sT[ns + j + 2][c];
            cur.w += la * sT[ns + j + 3][c];
            *(float4*)(out + ob + j) = cur;
        }
    }
}

extern "C" void kernel_launch(void* const* d_in, const int* in_sizes, int n_in,
                              void* d_out, int out_size, void* d_ws, size_t ws_size,
                              hipStream_t stream) {
    const float* x    = (const float*)d_in[0];
    const float* Wq   = (const float*)d_in[1];
    const float* Wk   = (const float*)d_in[2];
    const float* Wv   = (const float*)d_in[3];
    const float* qw   = (const float*)d_in[4];
    const float* qb   = (const float*)d_in[5];
    const float* kw   = (const float*)d_in[6];
    const float* kb   = (const float*)d_in[7];
    const float* vw   = (const float*)d_in[8];
    const float* vb   = (const float*)d_in[9];
    const float* lam1 = (const float*)d_in[10];
    const float* lam2 = (const float*)d_in[11];
    float* out = (float*)d_out;

    char* W = (char*)d_ws;
    float*   xpe  = (float*)(W);                                   // 2 MB
    ushortT* Qb   = (ushortT*)(W + (2u << 20));                    // 1 MB
    ushortT* Kb   = (ushortT*)(W + (3u << 20));                    // 1 MB
    ushortT* Vtb  = (ushortT*)(W + (4u << 20));                    // 1 MB
    ushortT* Mtb  = (ushortT*)(W + (5u << 20));                    // 128 KB
    ushortT* Ntb  = (ushortT*)(W + (5u << 20) + (1u << 17));       // 128 KB
    ushortT* Wvtb = (ushortT*)(W + (5u << 20) + (2u << 17));       // 1 MB
    float*   pM   = (float*)(W + (6u << 20) + (2u << 17));         // 128 KB
    float*   pL   = (float*)(W + (6u << 20) + (3u << 17));         // 128 KB
    float*   pAcc = (float*)(W + (6u << 20) + (4u << 17));         // 8 MB  (ends ~14.5 MB)

    // 1. x_pe
    k_xpe<<<dim3(BB * CC * NN / 256), dim3(256), 0, stream>>>(x, xpe);
    // 2. Q,K,V projections (bf16; V transposed; scale folded into Q)
    k_qkv<<<dim3(16, 3, BB), dim3(256), 0, stream>>>(xpe, Wq, Wk, Wv, Qb, Kb, Vtb);
    // 3. convs -> Mt, Nt (n,8), WvT (64,n); log2e folded into Mt
    k_conv<<<dim3(32, 5, BB), dim3(256), 0, stream>>>(xpe, qw, qb, kw, kb, vw, vb,
                                                      Mtb, Ntb, Wvtb);
    // 4. TSA MFMA flash + fused reduce/epilogue
    k_flash_mfma<64><<<dim3(NN / 64, NJ, BB), dim3(256), 0, stream>>>(
        Qb, Kb, Vtb, pM, pL, pAcc);
    k_reduce_out<<<dim3(NN / 64, BB), dim3(256), 0, stream>>>(
        pM, pL, pAcc, xpe, lam1, out, 0);
    // 5. GSA MFMA flash + fused reduce/epilogue (accumulate)
    k_flash_mfma<8><<<dim3(NN / 64, NJ, BB), dim3(256), 0, stream>>>(
        Mtb, Ntb, Wvtb, pM, pL, pAcc);
    k_reduce_out<<<dim3(NN / 64, BB), dim3(256), 0, stream>>>(
        pM, pL, pAcc, xpe, lam2, out, 1);
}

// Round 3
// 263.228 us; speedup vs baseline: 3.7984x; 1.6528x over previous
//
#include <hip/hip_runtime.h>
#include <math.h>

// Problem constants
#define BB 2
#define CC 64
#define NN 4096      // 16*16*16
#define CN (CC*NN)   // 262144
#define NJ 4         // j-split chunks for flash partials

#define LOG2E 1.4426950408889634f
#define QSCALE 0.18033688011112042f   // log2e / sqrt(64)

#define XT_ROWS 4097                  // row 0 = zero guard row

typedef __attribute__((ext_vector_type(8))) short short8;
typedef __attribute__((ext_vector_type(4))) float float4v;
typedef unsigned short ushortT;

__device__ __forceinline__ ushortT f2bf(float x) {
    union { float f; unsigned u; } v; v.f = x;
    unsigned r = v.u + 0x7FFF + ((v.u >> 16) & 1);   // RNE
    return (ushortT)(r >> 16);
}

// ---------------- PE ----------------
__device__ __forceinline__ float pe_val(int c, int hx, int wy, int dz) {
    int pos, c2;
    if (c < 22)      { pos = hx; c2 = c; }
    else if (c < 44) { pos = wy; c2 = c - 22; }
    else             { pos = dz; c2 = c - 44; }
    int is_cos = (c2 >= 11);
    int k = c2 - (is_cos ? 11 : 0);
    float freq = exp2f(-1.2079738526863135f * (float)k);
    float arg = (float)pos * freq;
    return is_cos ? cosf(arg) : sinf(arg);
}

// ---------------- x_pe (fp32, (b,c,n)) + transposed bf16 Xt (b,pos,ic) ----------------
// grid (NN/64, BB), 256 threads
__global__ __launch_bounds__(256) void k_xpe(const float* __restrict__ x,
                                             float* __restrict__ xpe,
                                             ushortT* __restrict__ Xt) {
    __shared__ float sT[64][65];
    int t = threadIdx.x;
    int b = blockIdx.y;
    int pos0 = blockIdx.x * 64;
    int pin = t & 63, cg = t >> 6;
    #pragma unroll
    for (int pass = 0; pass < 16; pass++) {
        int c = pass * 4 + cg;
        int pos = pos0 + pin;
        int dz = pos & 15, wy = (pos >> 4) & 15, hx = pos >> 8;
        size_t gi = (size_t)(b * 64 + c) * NN + pos;
        float v = x[gi] + pe_val(c, hx, wy, dz);
        xpe[gi] = v;
        sT[c][pin] = v;
    }
    __syncthreads();
    int icn = t & 63, pg = t >> 6;
    #pragma unroll
    for (int pass = 0; pass < 16; pass++) {
        int po = pass * 4 + pg;
        Xt[((size_t)b * XT_ROWS + pos0 + po + 1) * 64 + icn] = f2bf(sT[icn][po]);
    }
    if (blockIdx.x == 0 && t < 64)
        Xt[((size_t)b * XT_ROWS) * 64 + t] = 0;   // zero guard row
}

// ---------------- weight reorg: Wr[tap][oc(80)][ic(64)] bf16 ----------------
// oc 0..7 = M (qw, xLOG2E), 8..15 = Nk (kw), 16..79 = Wv (vw)
__global__ __launch_bounds__(256) void k_wreorg(const float* __restrict__ qw,
                                                const float* __restrict__ kw,
                                                const float* __restrict__ vw,
                                                ushortT* __restrict__ Wr) {
    int idx = blockIdx.x * 256 + threadIdx.x;   // 27*80*64 = 138240
    int ic = idx & 63;
    int oc = (idx >> 6) % 80;
    int tap = idx / 5120;
    float v;
    if (oc < 8)       v = qw[(oc * 64 + ic) * 27 + tap] * LOG2E;
    else if (oc < 16) v = kw[((oc - 8) * 64 + ic) * 27 + tap];
    else              v = vw[((oc - 16) * 64 + ic) * 27 + tap];
    Wr[idx] = f2bf(v);
}

// ---------------- Conv3d via per-tap MFMA implicit GEMM ----------------
// grid (NN/256, 5, BB), 256 thr = 4 waves; wave: 16 oc x 64 pos. No LDS, no barriers.
__global__ __launch_bounds__(256) void k_conv_mfma(const ushortT* __restrict__ Xt,
                                                   const ushortT* __restrict__ Wr,
                                                   const float* __restrict__ qb,
                                                   const float* __restrict__ kb,
                                                   const float* __restrict__ vb,
                                                   ushortT* __restrict__ Mt,
                                                   ushortT* __restrict__ Nt,
                                                   ushortT* __restrict__ Wvt) {
    int t = threadIdx.x;
    int wv = t >> 6, l = t & 63, p = l & 15, q = l >> 4;
    int b = blockIdx.z, ocg = blockIdx.y;
    int pos0 = blockIdx.x * 256 + wv * 64;

    const ushortT* xb = Xt + (size_t)b * XT_ROWS * 64;

    float4v acc[4];
    int posf[4], hxf[4], wyf[4], dzf[4];
    #pragma unroll
    for (int f = 0; f < 4; f++) {
        acc[f] = (float4v)0.f;
        posf[f] = pos0 + f * 16 + p;
        dzf[f] = posf[f] & 15; wyf[f] = (posf[f] >> 4) & 15; hxf[f] = posf[f] >> 8;
    }

    #pragma unroll
    for (int tap = 0; tap < 27; tap++) {
        const int dh = tap / 9 - 1, dw = (tap / 3) % 3 - 1, dd = tap % 3 - 1;
        const int shift = dh * 256 + dw * 16 + dd;
        const ushortT* wrow = Wr + ((size_t)tap * 80 + ocg * 16 + p) * 64 + q * 8;
        short8 a0 = *(const short8*)(wrow);
        short8 a1 = *(const short8*)(wrow + 32);
        #pragma unroll
        for (int f = 0; f < 4; f++) {
            bool ok = ((unsigned)(hxf[f] + dh) < 16u) &&
                      ((unsigned)(wyf[f] + dw) < 16u) &&
                      ((unsigned)(dzf[f] + dd) < 16u);
            int row = ok ? (posf[f] + shift + 1) : 0;
            const ushortT* xrow = xb + (size_t)row * 64 + q * 8;
            short8 b0 = *(const short8*)xrow;
            short8 b1 = *(const short8*)(xrow + 32);
            acc[f] = __builtin_amdgcn_mfma_f32_16x16x32_bf16(a0, b0, acc[f], 0, 0, 0);
            acc[f] = __builtin_amdgcn_mfma_f32_16x16x32_bf16(a1, b1, acc[f], 0, 0, 0);
        }
    }

    // epilogue: C-layout lane holds oc_local = q*4+r, pos = posf[f]
    if (ocg == 0) {
        #pragma unroll
        for (int f = 0; f < 4; f++) {
            #pragma unroll
            for (int r = 0; r < 4; r++) {
                int ol = q * 4 + r;
                int pos = posf[f];
                float v = acc[f][r];
                if (ol < 8)
                    Mt[((size_t)(b * NN + pos)) * 8 + ol] = f2bf(v + qb[ol] * LOG2E);
                else
                    Nt[((size_t)(b * NN + pos)) * 8 + (ol - 8)] = f2bf(v + kb[ol - 8]);
            }
        }
    } else {
        #pragma unroll
        for (int f = 0; f < 4; f++) {
            #pragma unroll
            for (int r = 0; r < 4; r++) {
                int oc = (ocg - 1) * 16 + q * 4 + r;
                int pos = posf[f];
                Wvt[((size_t)(b * 64 + oc)) * NN + pos] = f2bf(acc[f][r] + vb[oc]);
            }
        }
    }
}

// ---------------- QKV projection (bf16 out; V transposed) ----------------
__global__ __launch_bounds__(256) void k_qkv(const float* __restrict__ xpe,
                                             const float* __restrict__ Wq,
                                             const float* __restrict__ Wk,
                                             const float* __restrict__ Wv,
                                             ushortT* __restrict__ Qb,
                                             ushortT* __restrict__ Kb,
                                             ushortT* __restrict__ Vtb) {
    __shared__ float sW[64 * 64];
    int t = threadIdx.x;
    int mat = blockIdx.y, b = blockIdx.z;
    const float* W = (mat == 0) ? Wq : (mat == 1) ? Wk : Wv;

    float4* sW4 = (float4*)sW;
    const float4* W4 = (const float4*)W;
    #pragma unroll
    for (int j = 0; j < 4; j++) sW4[j * 256 + t] = W4[j * 256 + t];
    __syncthreads();

    int i = blockIdx.x * 256 + t;
    float acc[64];
    #pragma unroll
    for (int d = 0; d < 64; d++) acc[d] = 0.f;

    const float* xp = xpe + b * CN + i;
    for (int c = 0; c < 64; c++) {
        float xv = xp[c * NN];
        #pragma unroll
        for (int d4 = 0; d4 < 16; d4++) {
            float4 wv = *(float4*)&sW[c * 64 + d4 * 4];
            acc[4 * d4 + 0] += xv * wv.x;
            acc[4 * d4 + 1] += xv * wv.y;
            acc[4 * d4 + 2] += xv * wv.z;
            acc[4 * d4 + 3] += xv * wv.w;
        }
    }
    if (mat < 2) {
        float sc = (mat == 0) ? QSCALE : 1.f;
        ushortT* o = ((mat == 0) ? Qb : Kb) + ((size_t)(b * NN + i)) * 64;
        #pragma unroll
        for (int d4 = 0; d4 < 16; d4++) {
            ushort4 u;
            u.x = f2bf(acc[4*d4+0] * sc); u.y = f2bf(acc[4*d4+1] * sc);
            u.z = f2bf(acc[4*d4+2] * sc); u.w = f2bf(acc[4*d4+3] * sc);
            *(ushort4*)(o + d4 * 4) = u;
        }
    } else {
        #pragma unroll
        for (int d = 0; d < 64; d++)
            Vtb[((size_t)(b * 64 + d)) * NN + i] = f2bf(acc[d]);
    }
}

// ---------------- MFMA flash attention partials (j-split) ----------------
template<int DQ>
__global__ __launch_bounds__(256) void k_flash_mfma(const ushortT* __restrict__ Qm,
                                                    const ushortT* __restrict__ Km,
                                                    const ushortT* __restrict__ Vt,
                                                    float* __restrict__ pM, float* __restrict__ pL,
                                                    float* __restrict__ pAcc) {
    constexpr int KCH = (DQ == 64) ? 2 : 1;
    __shared__ ushortT sP[4][16 * 64];
    int t = threadIdx.x;
    int w = t >> 6, l = t & 63;
    int lane15 = l & 15, q = l >> 4;
    int b = blockIdx.z, jc = blockIdx.y;
    int i0 = blockIdx.x * 64 + w * 16;
    ushortT* myP = sP[w];

    short8 qf[KCH];
    {
        const ushortT* qrow = Qm + ((size_t)(b * NN + i0 + lane15)) * DQ;
        #pragma unroll
        for (int kc = 0; kc < KCH; kc++) {
            if (DQ == 64) {
                qf[kc] = *(const short8*)(qrow + kc * 32 + q * 8);
            } else {
                short8 z = (short8)0;
                if (q == 0) z = *(const short8*)qrow;
                qf[kc] = z;
            }
        }
    }

    float m[4], l_[4];
    float4v O[4];
    #pragma unroll
    for (int r = 0; r < 4; r++) { m[r] = -3e38f; l_[r] = 0.f; }
    #pragma unroll
    for (int cs = 0; cs < 4; cs++) O[cs] = (float4v)0.f;

    const int jbase0 = jc * (NN / NJ);
    for (int jt = 0; jt < (NN / NJ) / 64; jt++) {
        int jb = jbase0 + jt * 64;

        short8 kf[4][KCH];
        #pragma unroll
        for (int sub = 0; sub < 4; sub++) {
            const ushortT* krow = Km + ((size_t)(b * NN + jb + sub * 16 + lane15)) * DQ;
            #pragma unroll
            for (int kc = 0; kc < KCH; kc++) {
                if (DQ == 64) kf[sub][kc] = *(const short8*)(krow + kc * 32 + q * 8);
                else { short8 z = (short8)0; if (q == 0) z = *(const short8*)krow; kf[sub][kc] = z; }
            }
        }
        float4v s[4];
        #pragma unroll
        for (int sub = 0; sub < 4; sub++) {
            float4v acc = (float4v)0.f;
            #pragma unroll
            for (int kc = 0; kc < KCH; kc++)
                acc = __builtin_amdgcn_mfma_f32_16x16x32_bf16(qf[kc], kf[sub][kc], acc, 0, 0, 0);
            s[sub] = acc;
        }

        float mx[4];
        #pragma unroll
        for (int r = 0; r < 4; r++)
            mx[r] = fmaxf(fmaxf(s[0][r], s[1][r]), fmaxf(s[2][r], s[3][r]));
        #pragma unroll
        for (int r = 0; r < 4; r++) {
            mx[r] = fmaxf(mx[r], __shfl_xor(mx[r], 1));
            mx[r] = fmaxf(mx[r], __shfl_xor(mx[r], 2));
            mx[r] = fmaxf(mx[r], __shfl_xor(mx[r], 4));
            mx[r] = fmaxf(mx[r], __shfl_xor(mx[r], 8));
        }
        float corr[4];
        #pragma unroll
        for (int r = 0; r < 4; r++) {
            float mn = fmaxf(m[r], mx[r]);
            corr[r] = exp2f(m[r] - mn);
            m[r] = mn;
        }
        #pragma unroll
        for (int sub = 0; sub < 4; sub++)
            #pragma unroll
            for (int r = 0; r < 4; r++)
                s[sub][r] = exp2f(s[sub][r] - m[r]);
        float rs[4];
        #pragma unroll
        for (int r = 0; r < 4; r++) {
            rs[r] = (s[0][r] + s[1][r]) + (s[2][r] + s[3][r]);
            rs[r] += __shfl_xor(rs[r], 1);
            rs[r] += __shfl_xor(rs[r], 2);
            rs[r] += __shfl_xor(rs[r], 4);
            rs[r] += __shfl_xor(rs[r], 8);
            l_[r] = l_[r] * corr[r] + rs[r];
        }
        #pragma unroll
        for (int cs = 0; cs < 4; cs++)
            #pragma unroll
            for (int r = 0; r < 4; r++)
                O[cs][r] *= corr[r];

        #pragma unroll
        for (int sub = 0; sub < 4; sub++) {
            int jgrp = sub * 2 + (lane15 >> 3);
            int e = lane15 & 7;
            #pragma unroll
            for (int r = 0; r < 4; r++) {
                int row = q * 4 + r;
                myP[row * 64 + ((jgrp ^ (row & 7)) * 8 + e)] = f2bf(s[sub][r]);
            }
        }
        short8 pf[2];
        #pragma unroll
        for (int kc2 = 0; kc2 < 2; kc2++)
            pf[kc2] = *(const short8*)(myP + lane15 * 64 + (((kc2 * 4 + q) ^ (lane15 & 7)) * 8));

        #pragma unroll
        for (int sub = 0; sub < 4; sub++) {
            const ushortT* vrow = Vt + ((size_t)(b * 64 + sub * 16 + lane15)) * NN + jb;
            short8 vf0 = *(const short8*)(vrow + q * 8);
            short8 vf1 = *(const short8*)(vrow + 32 + q * 8);
            O[sub] = __builtin_amdgcn_mfma_f32_16x16x32_bf16(pf[0], vf0, O[sub], 0, 0, 0);
            O[sub] = __builtin_amdgcn_mfma_f32_16x16x32_bf16(pf[1], vf1, O[sub], 0, 0, 0);
        }
    }

    size_t base = (size_t)(b * NJ + jc) * NN + i0;
    if (lane15 == 0) {
        #pragma unroll
        for (int r = 0; r < 4; r++) {
            pM[base + q * 4 + r] = m[r];
            pL[base + q * 4 + r] = l_[r];
        }
    }
    #pragma unroll
    for (int cs = 0; cs < 4; cs++)
        #pragma unroll
        for (int r = 0; r < 4; r++)
            pAcc[(base + q * 4 + r) * 64 + cs * 16 + lane15] = O[cs][r];
}

// ---------------- Reduce partials + fused epilogue ----------------
__global__ __launch_bounds__(256) void k_reduce_out(const float* __restrict__ pM,
                                                    const float* __restrict__ pL,
                                                    const float* __restrict__ pAcc,
                                                    const float* __restrict__ xpe,
                                                    const float* __restrict__ lam,
                                                    float* __restrict__ out,
                                                    int add_mode) {
    __shared__ float sT[64][65];
    int t = threadIdx.x;
    int b = blockIdx.y;
    int n0 = blockIdx.x * 64;
    int pp = t >> 2, seg = t & 3;
    int n = n0 + pp;

    float mv[NJ], M = -3e38f;
    #pragma unroll
    for (int jc = 0; jc < NJ; jc++) {
        mv[jc] = pM[(size_t)(b * NJ + jc) * NN + n];
        M = fmaxf(M, mv[jc]);
    }
    float L = 0.f;
    float v[16];
    #pragma unroll
    for (int e = 0; e < 16; e++) v[e] = 0.f;
    #pragma unroll
    for (int jc = 0; jc < NJ; jc++) {
        float wgt = exp2f(mv[jc] - M);
        L += pL[(size_t)(b * NJ + jc) * NN + n] * wgt;
        const float4* pa = (const float4*)(pAcc + ((size_t)(b * NJ + jc) * NN + n) * 64 + seg * 16);
        #pragma unroll
        for (int e4 = 0; e4 < 4; e4++) {
            float4 x = pa[e4];
            v[4*e4+0] += wgt * x.x; v[4*e4+1] += wgt * x.y;
            v[4*e4+2] += wgt * x.z; v[4*e4+3] += wgt * x.w;
        }
    }
    float invL = 1.f / L;
    #pragma unroll
    for (int e = 0; e < 16; e++) sT[pp][seg * 16 + e] = v[e] * invL;
    __syncthreads();

    int c = t >> 2, ns = (t & 3) * 16;
    float la = lam[0];
    size_t ob = ((size_t)(b * 64 + c)) * NN + n0 + ns;
    if (!add_mode) {
        const float* xp = xpe + ob;
        #pragma unroll
        for (int j = 0; j < 16; j += 4) {
            float4 ov;
            ov.x = la * sT[ns + j + 0][c] + xp[j + 0];
            ov.y = la * sT[ns + j + 1][c] + xp[j + 1];
            ov.z = la * sT[ns + j + 2][c] + xp[j + 2];
            ov.w = la * sT[ns + j + 3][c] + xp[j + 3];
            *(float4*)(out + ob + j) = ov;
        }
    } else {
        #pragma unroll
        for (int j = 0; j < 16; j += 4) {
            float4 cur = *(const float4*)(out + ob + j);
            cur.x += la * sT[ns + j + 0][c];
            cur.y += la * sT[ns + j + 1][c];
            cur.z += la * sT[ns + j + 2][c];
            cur.w += la * sT[ns + j + 3][c];
            *(float4*)(out + ob + j) = cur;
        }
    }
}

extern "C" void kernel_launch(void* const* d_in, const int* in_sizes, int n_in,
                              void* d_out, int out_size, void* d_ws, size_t ws_size,
                              hipStream_t stream) {
    const float* x    = (const float*)d_in[0];
    const float* Wq   = (const float*)d_in[1];
    const float* Wk   = (const float*)d_in[2];
    const float* Wv   = (const float*)d_in[3];
    const float* qw   = (const float*)d_in[4];
    const float* qb   = (const float*)d_in[5];
    const float* kw   = (const float*)d_in[6];
    const float* kb   = (const float*)d_in[7];
    const float* vw   = (const float*)d_in[8];
    const float* vb   = (const float*)d_in[9];
    const float* lam1 = (const float*)d_in[10];
    const float* lam2 = (const float*)d_in[11];
    float* out = (float*)d_out;

    char* W = (char*)d_ws;
    float*   xpe  = (float*)(W);                                   // 2 MB
    ushortT* Qb   = (ushortT*)(W + (2u << 20));                    // 1 MB
    ushortT* Kb   = (ushortT*)(W + (3u << 20));                    // 1 MB
    ushortT* Vtb  = (ushortT*)(W + (4u << 20));                    // 1 MB
    ushortT* Mtb  = (ushortT*)(W + (5u << 20));                    // 128 KB
    ushortT* Ntb  = (ushortT*)(W + (5u << 20) + (1u << 17));       // 128 KB
    ushortT* Wvtb = (ushortT*)(W + (5u << 20) + (2u << 17));       // 1 MB
    float*   pM   = (float*)(W + (6u << 20) + (2u << 17));         // 128 KB
    float*   pL   = (float*)(W + (6u << 20) + (3u << 17));         // 128 KB
    float*   pAcc = (float*)(W + (6u << 20) + (4u << 17));         // 8 MB (ends 14.5 MB)
    ushortT* Xt   = (ushortT*)(W + (15u << 20));                   // 2*4097*64*2B ~ 1.0 MB
    ushortT* Wr   = (ushortT*)(W + (16u << 20) + (1u << 19));      // 270 KB (ends ~16.8 MB)

    // 1. x_pe (fp32) + Xt (bf16 transposed, guard row)
    k_xpe<<<dim3(NN / 64, BB), dim3(256), 0, stream>>>(x, xpe, Xt);
    // 1b. weight reorg
    k_wreorg<<<dim3(27 * 80 * 64 / 256), dim3(256), 0, stream>>>(qw, kw, vw, Wr);
    // 2. Q,K,V projections
    k_qkv<<<dim3(16, 3, BB), dim3(256), 0, stream>>>(xpe, Wq, Wk, Wv, Qb, Kb, Vtb);
    // 3. conv via MFMA implicit GEMM
    k_conv_mfma<<<dim3(NN / 256, 5, BB), dim3(256), 0, stream>>>(
        Xt, Wr, qb, kb, vb, Mtb, Ntb, Wvtb);
    // 4. TSA flash + fused reduce/epilogue
    k_flash_mfma<64><<<dim3(NN / 64, NJ, BB), dim3(256), 0, stream>>>(
        Qb, Kb, Vtb, pM, pL, pAcc);
    k_reduce_out<<<dim3(NN / 64, BB), dim3(256), 0, stream>>>(
        pM, pL, pAcc, xpe, lam1, out, 0);
    // 5. GSA flash + fused reduce/epilogue (accumulate)
    k_flash_mfma<8><<<dim3(NN / 64, NJ, BB), dim3(256), 0, stream>>>(
        Mtb, Ntb, Wvtb, pM, pL, pAcc);
    k_reduce_out<<<dim3(NN / 64, BB), dim3(256), 0, stream>>>(
        pM, pL, pAcc, xpe, lam2, out, 1);
}

// Round 4
// 239.996 us; speedup vs baseline: 4.1661x; 1.0968x over previous
//
#include <hip/hip_runtime.h>
#include <math.h>

// Problem constants
#define BB 2
#define CC 64
#define NN 4096      // 16*16*16
#define CN (CC*NN)
#define NJ 4         // j-split chunks for flash partials
#define NT ((NN/NJ)/64)   // 16 j-tiles per chunk

#define LOG2E 1.4426950408889634f
#define QSCALE 0.18033688011112042f   // log2e / sqrt(64)

#define XT_ROWS 4097                  // row 0 = zero guard row
#define WQKV_OFF (27*80*64)           // offset of transposed QKV weights inside Wr

typedef __attribute__((ext_vector_type(8))) short short8;
typedef __attribute__((ext_vector_type(4))) float float4v;
typedef unsigned short ushortT;

__device__ __forceinline__ ushortT f2bf(float x) {
    union { float f; unsigned u; } v; v.f = x;
    unsigned r = v.u + 0x7FFF + ((v.u >> 16) & 1);   // RNE
    return (ushortT)(r >> 16);
}
__device__ __forceinline__ float bf2f(short s) {
    union { unsigned u; float f; } v;
    v.u = ((unsigned)(unsigned short)s) << 16;
    return v.f;
}

// ---------------- PE ----------------
__device__ __forceinline__ float pe_val(int c, int hx, int wy, int dz) {
    int pos, c2;
    if (c < 22)      { pos = hx; c2 = c; }
    else if (c < 44) { pos = wy; c2 = c - 22; }
    else             { pos = dz; c2 = c - 44; }
    int is_cos = (c2 >= 11);
    int k = c2 - (is_cos ? 11 : 0);
    float freq = exp2f(-1.2079738526863135f * (float)k);
    float arg = (float)pos * freq;
    return is_cos ? cosf(arg) : sinf(arg);
}

// ---------------- x_pe (fp32, (b,c,n)) + transposed bf16 Xt (b,pos,ic) ----------------
__global__ __launch_bounds__(256) void k_xpe(const float* __restrict__ x,
                                             float* __restrict__ xpe,
                                             ushortT* __restrict__ Xt) {
    __shared__ float sT[64][65];
    int t = threadIdx.x;
    int b = blockIdx.y;
    int pos0 = blockIdx.x * 64;
    int pin = t & 63, cg = t >> 6;
    #pragma unroll
    for (int pass = 0; pass < 16; pass++) {
        int c = pass * 4 + cg;
        int pos = pos0 + pin;
        int dz = pos & 15, wy = (pos >> 4) & 15, hx = pos >> 8;
        size_t gi = (size_t)(b * 64 + c) * NN + pos;
        float v = x[gi] + pe_val(c, hx, wy, dz);
        xpe[gi] = v;
        sT[c][pin] = v;
    }
    __syncthreads();
    int icn = t & 63, pg = t >> 6;
    #pragma unroll
    for (int pass = 0; pass < 16; pass++) {
        int po = pass * 4 + pg;
        Xt[((size_t)b * XT_ROWS + pos0 + po + 1) * 64 + icn] = f2bf(sT[icn][po]);
    }
    if (blockIdx.x == 0 && t < 64)
        Xt[((size_t)b * XT_ROWS) * 64 + t] = 0;   // zero guard row
}

// ---------------- weight reorg ----------------
// [0, 27*80*64): Wr[tap][oc(80)][ic]  (oc 0..7 = qw*LOG2E, 8..15 = kw, 16..79 = vw)
// [WQKV_OFF, +3*64*64): Wt[mat][d][c] = W_mat[c][d]  (mat 0 = Wq*QSCALE, 1 = Wk, 2 = Wv)
__global__ __launch_bounds__(256) void k_wreorg(const float* __restrict__ qw,
                                                const float* __restrict__ kw,
                                                const float* __restrict__ vw,
                                                const float* __restrict__ Wq,
                                                const float* __restrict__ Wk,
                                                const float* __restrict__ Wv,
                                                ushortT* __restrict__ Wr) {
    int idx = blockIdx.x * 256 + threadIdx.x;
    if (idx < WQKV_OFF) {
        int ic = idx & 63;
        int oc = (idx >> 6) % 80;
        int tap = idx / 5120;
        float v;
        if (oc < 8)       v = qw[(oc * 64 + ic) * 27 + tap] * LOG2E;
        else if (oc < 16) v = kw[((oc - 8) * 64 + ic) * 27 + tap];
        else              v = vw[((oc - 16) * 64 + ic) * 27 + tap];
        Wr[idx] = f2bf(v);
    } else if (idx < WQKV_OFF + 3 * 64 * 64) {
        int idx2 = idx - WQKV_OFF;
        int c = idx2 & 63, d = (idx2 >> 6) & 63, mat = idx2 >> 12;
        const float* Wm = (mat == 0) ? Wq : (mat == 1) ? Wk : Wv;
        float v = Wm[c * 64 + d] * ((mat == 0) ? QSCALE : 1.f);
        Wr[idx] = f2bf(v);
    }
}

// ---------------- QKV projection via MFMA ----------------
// grid (64, 3, BB), 4 waves; wave = 16 rows x 64 cols, K=64.
__global__ __launch_bounds__(256) void k_qkv_mfma(const ushortT* __restrict__ Xt,
                                                  const ushortT* __restrict__ Wt3,
                                                  ushortT* __restrict__ Qb,
                                                  ushortT* __restrict__ Kb,
                                                  ushortT* __restrict__ Vtb) {
    int t = threadIdx.x, w = t >> 6, l = t & 63;
    int lane15 = l & 15, q = l >> 4;
    int mat = blockIdx.y, b = blockIdx.z;
    int i0 = blockIdx.x * 64 + w * 16;

    const ushortT* Wt = Wt3 + mat * 4096;
    const ushortT* xrow = Xt + ((size_t)b * XT_ROWS + i0 + lane15 + 1) * 64;
    short8 a0 = *(const short8*)(xrow + q * 8);
    short8 a1 = *(const short8*)(xrow + 32 + q * 8);

    float4v acc[4];
    #pragma unroll
    for (int cg = 0; cg < 4; cg++) {
        const ushortT* wrow = Wt + (cg * 16 + lane15) * 64;
        short8 b0 = *(const short8*)(wrow + q * 8);
        short8 b1 = *(const short8*)(wrow + 32 + q * 8);
        float4v a = (float4v)0.f;
        a = __builtin_amdgcn_mfma_f32_16x16x32_bf16(a0, b0, a, 0, 0, 0);
        a = __builtin_amdgcn_mfma_f32_16x16x32_bf16(a1, b1, a, 0, 0, 0);
        acc[cg] = a;
    }

    if (mat < 2) {
        ushortT* o = (mat == 0) ? Qb : Kb;
        #pragma unroll
        for (int cg = 0; cg < 4; cg++)
            #pragma unroll
            for (int r = 0; r < 4; r++)
                o[((size_t)(b * NN + i0 + q * 4 + r)) * 64 + cg * 16 + lane15] = f2bf(acc[cg][r]);
    } else {
        #pragma unroll
        for (int cg = 0; cg < 4; cg++)
            #pragma unroll
            for (int r = 0; r < 4; r++)
                Vtb[((size_t)(b * 64 + cg * 16 + lane15)) * NN + i0 + q * 4 + r] = f2bf(acc[cg][r]);
    }
}

// ---------------- Conv3d via per-tap MFMA implicit GEMM ----------------
// grid (64, 5, BB), 4 waves; wave = 16 pos x 16 oc. No LDS, no barriers.
__global__ __launch_bounds__(256) void k_conv_mfma(const ushortT* __restrict__ Xt,
                                                   const ushortT* __restrict__ Wr,
                                                   const float* __restrict__ qb,
                                                   const float* __restrict__ kb,
                                                   const float* __restrict__ vb,
                                                   ushortT* __restrict__ Mt,
                                                   ushortT* __restrict__ Nt,
                                                   ushortT* __restrict__ Wvt) {
    int t = threadIdx.x;
    int wv = t >> 6, l = t & 63, p = l & 15, q = l >> 4;
    int b = blockIdx.z, ocg = blockIdx.y;
    int pos0 = blockIdx.x * 64 + wv * 16;

    const ushortT* xb = Xt + (size_t)b * XT_ROWS * 64;
    int pos = pos0 + p;
    int dz = pos & 15, wy = (pos >> 4) & 15, hx = pos >> 8;
    float4v acc = (float4v)0.f;

    #pragma unroll
    for (int tap = 0; tap < 27; tap++) {
        const int dh = tap / 9 - 1, dw = (tap / 3) % 3 - 1, dd = tap % 3 - 1;
        const int shift = dh * 256 + dw * 16 + dd;
        const ushortT* wrow = Wr + ((size_t)tap * 80 + ocg * 16 + p) * 64 + q * 8;
        short8 a0 = *(const short8*)(wrow);
        short8 a1 = *(const short8*)(wrow + 32);
        bool ok = ((unsigned)(hx + dh) < 16u) &&
                  ((unsigned)(wy + dw) < 16u) &&
                  ((unsigned)(dz + dd) < 16u);
        int row = ok ? (pos + shift + 1) : 0;
        const ushortT* xrow = xb + (size_t)row * 64 + q * 8;
        short8 b0 = *(const short8*)xrow;
        short8 b1 = *(const short8*)(xrow + 32);
        acc = __builtin_amdgcn_mfma_f32_16x16x32_bf16(a0, b0, acc, 0, 0, 0);
        acc = __builtin_amdgcn_mfma_f32_16x16x32_bf16(a1, b1, acc, 0, 0, 0);
    }

    if (ocg == 0) {
        #pragma unroll
        for (int r = 0; r < 4; r++) {
            int ol = q * 4 + r;
            float v = acc[r];
            if (ol < 8)
                Mt[((size_t)(b * NN + pos)) * 8 + ol] = f2bf(v + qb[ol] * LOG2E);
            else
                Nt[((size_t)(b * NN + pos)) * 8 + (ol - 8)] = f2bf(v + kb[ol - 8]);
        }
    } else {
        #pragma unroll
        for (int r = 0; r < 4; r++) {
            int oc = (ocg - 1) * 16 + q * 4 + r;
            Wvt[((size_t)(b * 64 + oc)) * NN + pos] = f2bf(acc[r] + vb[oc]);
        }
    }
}

// ---------------- MFMA flash body (shared by TSA / GSA) ----------------
template<int DQ>
__device__ __forceinline__ void flash_body(int it, int jc, int b, int w, int l,
                                           const ushortT* __restrict__ Qm,
                                           const ushortT* __restrict__ Km,
                                           const ushortT* __restrict__ Vt,
                                           float* __restrict__ pM, float* __restrict__ pL,
                                           ushortT* __restrict__ pAcc,
                                           ushortT* __restrict__ myP) {
    constexpr int KCH = (DQ == 64) ? 2 : 1;
    int lane15 = l & 15, q = l >> 4;
    int i0 = it * 64 + w * 16;

    short8 qf[KCH];
    {
        const ushortT* qrow = Qm + ((size_t)(b * NN + i0 + lane15)) * DQ;
        #pragma unroll
        for (int kc = 0; kc < KCH; kc++) {
            if (DQ == 64) qf[kc] = *(const short8*)(qrow + kc * 32 + q * 8);
            else { short8 z = (short8)0; if (q == 0) z = *(const short8*)qrow; qf[kc] = z; }
        }
    }

    float m[4], l_[4];
    float4v O[4];
    #pragma unroll
    for (int r = 0; r < 4; r++) { m[r] = -3e38f; l_[r] = 0.f; }
    #pragma unroll
    for (int cs = 0; cs < 4; cs++) O[cs] = (float4v)0.f;

    const int jbase0 = jc * (NN / NJ);

    // prefetch K for the first tile
    short8 kf[4][KCH];
    #pragma unroll
    for (int sub = 0; sub < 4; sub++) {
        const ushortT* krow = Km + ((size_t)(b * NN + jbase0 + sub * 16 + lane15)) * DQ;
        #pragma unroll
        for (int kc = 0; kc < KCH; kc++) {
            if (DQ == 64) kf[sub][kc] = *(const short8*)(krow + kc * 32 + q * 8);
            else { short8 z = (short8)0; if (q == 0) z = *(const short8*)krow; kf[sub][kc] = z; }
        }
    }

    for (int jt = 0; jt < NT; jt++) {
        int jb = jbase0 + jt * 64;

        // V loads for current tile (issued early; consumed at the end)
        short8 va[4], vb_[4];
        #pragma unroll
        for (int sub = 0; sub < 4; sub++) {
            const ushortT* vrow = Vt + ((size_t)(b * 64 + sub * 16 + lane15)) * NN + jb;
            va[sub]  = *(const short8*)(vrow + q * 8);
            vb_[sub] = *(const short8*)(vrow + 32 + q * 8);
        }

        // ---- S = Q K^T ----
        float4v s[4];
        #pragma unroll
        for (int sub = 0; sub < 4; sub++) {
            float4v acc = (float4v)0.f;
            #pragma unroll
            for (int kc = 0; kc < KCH; kc++)
                acc = __builtin_amdgcn_mfma_f32_16x16x32_bf16(qf[kc], kf[sub][kc], acc, 0, 0, 0);
            s[sub] = acc;
        }

        // ---- prefetch K for next tile (hidden behind softmax) ----
        short8 kfn[4][KCH];
        if (jt + 1 < NT) {
            #pragma unroll
            for (int sub = 0; sub < 4; sub++) {
                const ushortT* krow = Km + ((size_t)(b * NN + jb + 64 + sub * 16 + lane15)) * DQ;
                #pragma unroll
                for (int kc = 0; kc < KCH; kc++) {
                    if (DQ == 64) kfn[sub][kc] = *(const short8*)(krow + kc * 32 + q * 8);
                    else { short8 z = (short8)0; if (q == 0) z = *(const short8*)krow; kfn[sub][kc] = z; }
                }
            }
        }

        // ---- online softmax (log2 domain) ----
        float mx[4];
        #pragma unroll
        for (int r = 0; r < 4; r++)
            mx[r] = fmaxf(fmaxf(s[0][r], s[1][r]), fmaxf(s[2][r], s[3][r]));
        #pragma unroll
        for (int r = 0; r < 4; r++) {
            mx[r] = fmaxf(mx[r], __shfl_xor(mx[r], 1));
            mx[r] = fmaxf(mx[r], __shfl_xor(mx[r], 2));
            mx[r] = fmaxf(mx[r], __shfl_xor(mx[r], 4));
            mx[r] = fmaxf(mx[r], __shfl_xor(mx[r], 8));
        }
        float corr[4];
        #pragma unroll
        for (int r = 0; r < 4; r++) {
            float mn = fmaxf(m[r], mx[r]);
            corr[r] = exp2f(m[r] - mn);
            m[r] = mn;
        }
        #pragma unroll
        for (int sub = 0; sub < 4; sub++)
            #pragma unroll
            for (int r = 0; r < 4; r++)
                s[sub][r] = exp2f(s[sub][r] - m[r]);
        float rs[4];
        #pragma unroll
        for (int r = 0; r < 4; r++) {
            rs[r] = (s[0][r] + s[1][r]) + (s[2][r] + s[3][r]);
            rs[r] += __shfl_xor(rs[r], 1);
            rs[r] += __shfl_xor(rs[r], 2);
            rs[r] += __shfl_xor(rs[r], 4);
            rs[r] += __shfl_xor(rs[r], 8);
            l_[r] = l_[r] * corr[r] + rs[r];
        }
        #pragma unroll
        for (int cs = 0; cs < 4; cs++)
            #pragma unroll
            for (int r = 0; r < 4; r++)
                O[cs][r] *= corr[r];

        // ---- P -> LDS (C-layout -> A-layout, XOR swizzle) ----
        #pragma unroll
        for (int sub = 0; sub < 4; sub++) {
            int jgrp = sub * 2 + (lane15 >> 3);
            int e = lane15 & 7;
            #pragma unroll
            for (int r = 0; r < 4; r++) {
                int row = q * 4 + r;
                myP[row * 64 + ((jgrp ^ (row & 7)) * 8 + e)] = f2bf(s[sub][r]);
            }
        }
        short8 pf[2];
        #pragma unroll
        for (int kc2 = 0; kc2 < 2; kc2++)
            pf[kc2] = *(const short8*)(myP + lane15 * 64 + (((kc2 * 4 + q) ^ (lane15 & 7)) * 8));

        // ---- O += P V ----
        #pragma unroll
        for (int sub = 0; sub < 4; sub++) {
            O[sub] = __builtin_amdgcn_mfma_f32_16x16x32_bf16(pf[0], va[sub], O[sub], 0, 0, 0);
            O[sub] = __builtin_amdgcn_mfma_f32_16x16x32_bf16(pf[1], vb_[sub], O[sub], 0, 0, 0);
        }

        if (jt + 1 < NT) {
            #pragma unroll
            for (int sub = 0; sub < 4; sub++)
                #pragma unroll
                for (int kc = 0; kc < KCH; kc++)
                    kf[sub][kc] = kfn[sub][kc];
        }
    }

    size_t base = (size_t)(b * NJ + jc) * NN + i0;
    if (lane15 == 0) {
        #pragma unroll
        for (int r = 0; r < 4; r++) {
            pM[base + q * 4 + r] = m[r];
            pL[base + q * 4 + r] = l_[r];
        }
    }
    #pragma unroll
    for (int cs = 0; cs < 4; cs++)
        #pragma unroll
        for (int r = 0; r < 4; r++)
            pAcc[(base + q * 4 + r) * 64 + cs * 16 + lane15] = f2bf(O[cs][r]);
}

// ---------------- Merged flash kernel (TSA blocks 0..63, GSA blocks 64..127) ----------------
__global__ __launch_bounds__(256, 3) void k_flash(const ushortT* __restrict__ Qb,
                                                  const ushortT* __restrict__ Kb,
                                                  const ushortT* __restrict__ Vtb,
                                                  const ushortT* __restrict__ Mtb,
                                                  const ushortT* __restrict__ Ntb,
                                                  const ushortT* __restrict__ Wvtb,
                                                  float* __restrict__ pMt, float* __restrict__ pLt,
                                                  ushortT* __restrict__ pAccT,
                                                  float* __restrict__ pMg, float* __restrict__ pLg,
                                                  ushortT* __restrict__ pAccG) {
    __shared__ ushortT sP[4][16 * 64];
    int t = threadIdx.x, w = t >> 6, l = t & 63;
    int b = blockIdx.z, jc = blockIdx.y;
    if (blockIdx.x < 64)
        flash_body<64>(blockIdx.x, jc, b, w, l, Qb, Kb, Vtb, pMt, pLt, pAccT, sP[w]);
    else
        flash_body<8>(blockIdx.x - 64, jc, b, w, l, Mtb, Ntb, Wvtb, pMg, pLg, pAccG, sP[w]);
}

// ---------------- Reduce both partial sets + fused epilogue ----------------
__device__ __forceinline__ void reduce_set(const float* __restrict__ pM,
                                           const float* __restrict__ pL,
                                           const ushortT* __restrict__ pAcc,
                                           int b, int n, int seg, float* v) {
    float mv[NJ], M = -3e38f;
    #pragma unroll
    for (int jc = 0; jc < NJ; jc++) {
        mv[jc] = pM[(size_t)(b * NJ + jc) * NN + n];
        M = fmaxf(M, mv[jc]);
    }
    float L = 0.f;
    #pragma unroll
    for (int e = 0; e < 16; e++) v[e] = 0.f;
    #pragma unroll
    for (int jc = 0; jc < NJ; jc++) {
        float wgt = exp2f(mv[jc] - M);
        L += pL[(size_t)(b * NJ + jc) * NN + n] * wgt;
        const ushortT* pa = pAcc + ((size_t)(b * NJ + jc) * NN + n) * 64 + seg * 16;
        short8 x0 = *(const short8*)pa;
        short8 x1 = *(const short8*)(pa + 8);
        #pragma unroll
        for (int e = 0; e < 8; e++) {
            v[e]     += wgt * bf2f(x0[e]);
            v[8 + e] += wgt * bf2f(x1[e]);
        }
    }
    float invL = 1.f / L;
    #pragma unroll
    for (int e = 0; e < 16; e++) v[e] *= invL;
}

__global__ __launch_bounds__(256) void k_reduce_both(const float* __restrict__ pMt,
                                                     const float* __restrict__ pLt,
                                                     const ushortT* __restrict__ pAccT,
                                                     const float* __restrict__ pMg,
                                                     const float* __restrict__ pLg,
                                                     const ushortT* __restrict__ pAccG,
                                                     const float* __restrict__ xpe,
                                                     const float* __restrict__ lam1,
                                                     const float* __restrict__ lam2,
                                                     float* __restrict__ out) {
    __shared__ float sT[64][65];
    __shared__ float sG[64][65];
    int t = threadIdx.x;
    int b = blockIdx.y;
    int n0 = blockIdx.x * 64;
    int pp = t >> 2, seg = t & 3;
    int n = n0 + pp;

    float vt[16], vg[16];
    reduce_set(pMt, pLt, pAccT, b, n, seg, vt);
    reduce_set(pMg, pLg, pAccG, b, n, seg, vg);
    #pragma unroll
    for (int e = 0; e < 16; e++) {
        sT[pp][seg * 16 + e] = vt[e];
        sG[pp][seg * 16 + e] = vg[e];
    }
    __syncthreads();

    int c = t >> 2, ns = (t & 3) * 16;
    float la1 = lam1[0], la2 = lam2[0];
    size_t ob = ((size_t)(b * 64 + c)) * NN + n0 + ns;
    const float* xp = xpe + ob;
    #pragma unroll
    for (int j = 0; j < 16; j += 4) {
        float4 ov;
        ov.x = la1 * sT[ns + j + 0][c] + la2 * sG[ns + j + 0][c] + xp[j + 0];
        ov.y = la1 * sT[ns + j + 1][c] + la2 * sG[ns + j + 1][c] + xp[j + 1];
        ov.z = la1 * sT[ns + j + 2][c] + la2 * sG[ns + j + 2][c] + xp[j + 2];
        ov.w = la1 * sT[ns + j + 3][c] + la2 * sG[ns + j + 3][c] + xp[j + 3];
        *(float4*)(out + ob + j) = ov;
    }
}

extern "C" void kernel_launch(void* const* d_in, const int* in_sizes, int n_in,
                              void* d_out, int out_size, void* d_ws, size_t ws_size,
                              hipStream_t stream) {
    const float* x    = (const float*)d_in[0];
    const float* Wq   = (const float*)d_in[1];
    const float* Wk   = (const float*)d_in[2];
    const float* Wv   = (const float*)d_in[3];
    const float* qw   = (const float*)d_in[4];
    const float* qb   = (const float*)d_in[5];
    const float* kw   = (const float*)d_in[6];
    const float* kb   = (const float*)d_in[7];
    const float* vw   = (const float*)d_in[8];
    const float* vb   = (const float*)d_in[9];
    const float* lam1 = (const float*)d_in[10];
    const float* lam2 = (const float*)d_in[11];
    float* out = (float*)d_out;

    char* W = (char*)d_ws;
    float*   xpe   = (float*)(W);                              // 2 MB
    ushortT* Qb    = (ushortT*)(W + (2u << 20));               // 1 MB
    ushortT* Kb    = (ushortT*)(W + (3u << 20));               // 1 MB
    ushortT* Vtb   = (ushortT*)(W + (4u << 20));               // 1 MB
    ushortT* Mtb   = (ushortT*)(W + (5u << 20));               // 128 KB
    ushortT* Ntb   = (ushortT*)(W + (5u << 20) + (1u << 17));  // 128 KB
    ushortT* Wvtb  = (ushortT*)(W + (5u << 20) + (2u << 17));  // 1 MB
    ushortT* Xt    = (ushortT*)(W + (6u << 20) + (2u << 17));  // ~1.0 MB
    ushortT* Wr    = (ushortT*)(W + (7u << 20) + (4u << 17));  // ~0.3 MB
    float*   pMt   = (float*)(W + (8u << 20));                 // 128 KB
    float*   pLt   = (float*)(W + (8u << 20) + (1u << 17));    // 128 KB
    float*   pMg   = (float*)(W + (8u << 20) + (2u << 17));    // 128 KB
    float*   pLg   = (float*)(W + (8u << 20) + (3u << 17));    // 128 KB
    ushortT* pAccT = (ushortT*)(W + (8u << 20) + (4u << 17));  // 4 MB (bf16)
    ushortT* pAccG = (ushortT*)(W + (12u << 20) + (4u << 17)); // 4 MB (ends 16.5 MB)

    // 1. x_pe (fp32) + Xt (bf16 transposed, guard row)
    k_xpe<<<dim3(NN / 64, BB), dim3(256), 0, stream>>>(x, xpe, Xt);
    // 1b. weight reorg (conv taps + transposed QKV mats)
    k_wreorg<<<dim3((WQKV_OFF + 3 * 64 * 64 + 255) / 256), dim3(256), 0, stream>>>(
        qw, kw, vw, Wq, Wk, Wv, Wr);
    // 2. QKV via MFMA
    k_qkv_mfma<<<dim3(64, 3, BB), dim3(256), 0, stream>>>(Xt, Wr + WQKV_OFF, Qb, Kb, Vtb);
    // 3. conv via MFMA implicit GEMM
    k_conv_mfma<<<dim3(64, 5, BB), dim3(256), 0, stream>>>(
        Xt, Wr, qb, kb, vb, Mtb, Ntb, Wvtb);
    // 4. merged TSA+GSA flash
    k_flash<<<dim3(128, NJ, BB), dim3(256), 0, stream>>>(
        Qb, Kb, Vtb, Mtb, Ntb, Wvtb, pMt, pLt, pAccT, pMg, pLg, pAccG);
    // 5. merged reduce + epilogue
    k_reduce_both<<<dim3(NN / 64, BB), dim3(256), 0, stream>>>(
        pMt, pLt, pAccT, pMg, pLg, pAccG, xpe, lam1, lam2, out);
}